// Round 1
// baseline (653.624 us; speedup 1.0000x reference)
//
#include <hip/hip_runtime.h>
#include <hip/hip_bf16.h>

// MoE FFN top-2 sparse, bf16 MFMA. T=4096 tokens, D=1024, H=2816, E=8.
// ws layout (needs ~52.3 MB):
//   [0]      counts[8]
//   [256]    offs[8]
//   [512]    tlist[E*T] int      (131072 B)
//   [131584] wlist[E*T] float    (131072 B)
//   [262656] xbf[T*D] bf16       (8388608 B)
//   [8651264] hmat[8192*H] bf16  (46137344 B)

#define T_TOK 4096
#define DDIM 1024
#define HDIM 2816
#define NEXP 8

typedef __attribute__((ext_vector_type(8))) short short8;
typedef __attribute__((ext_vector_type(4))) short short4v;
typedef __attribute__((ext_vector_type(4))) float floatx4;

__device__ __forceinline__ short f2bf(float f) {
  union { float f; unsigned int u; } v; v.f = f;
  unsigned int u = v.u;
  u += 0x7FFFu + ((u >> 16) & 1u);   // round-to-nearest-even
  return (short)(u >> 16);
}

__global__ __launch_bounds__(256) void zero_kernel(float4* __restrict__ out4, int* __restrict__ counts) {
  int i = blockIdx.x * 256 + threadIdx.x;
  out4[i] = make_float4(0.f, 0.f, 0.f, 0.f);
  if (blockIdx.x == 0 && threadIdx.x < NEXP) counts[threadIdx.x] = 0;
}

__global__ __launch_bounds__(64) void gating_kernel(const float* __restrict__ x,
    const float* __restrict__ Wg, short* __restrict__ xbf,
    int* __restrict__ counts, int* __restrict__ tlist, float* __restrict__ wlist) {
  int t = blockIdx.x;
  int lane = threadIdx.x;
  const float* xt = x + (size_t)t * DDIM;
  float xr[16];
#pragma unroll
  for (int j = 0; j < 16; ++j) xr[j] = xt[j * 64 + lane];
  short* xbt = xbf + (size_t)t * DDIM;
#pragma unroll
  for (int j = 0; j < 16; ++j) xbt[j * 64 + lane] = f2bf(xr[j]);
  float s[NEXP];
#pragma unroll
  for (int e = 0; e < NEXP; ++e) {
    const float* wge = Wg + e * DDIM;
    float p = 0.f;
#pragma unroll
    for (int j = 0; j < 16; ++j) p += xr[j] * wge[j * 64 + lane];
#pragma unroll
    for (int o = 32; o > 0; o >>= 1) p += __shfl_xor(p, o, 64);
    s[e] = p;
  }
  if (lane == 0) {
    int e1 = 0; float s1 = s[0];
#pragma unroll
    for (int e = 1; e < NEXP; ++e) if (s[e] > s1) { s1 = s[e]; e1 = e; }
    int e2 = -1; float s2 = -1e30f;
#pragma unroll
    for (int e = 0; e < NEXP; ++e) if (e != e1 && s[e] > s2) { s2 = s[e]; e2 = e; }
    int slot = atomicAdd(&counts[e1], 1);
    tlist[e1 * T_TOK + slot] = t; wlist[e1 * T_TOK + slot] = s1;
    slot = atomicAdd(&counts[e2], 1);
    tlist[e2 * T_TOK + slot] = t; wlist[e2 * T_TOK + slot] = s2;
  }
}

__global__ void offsets_kernel(const int* __restrict__ counts, int* __restrict__ offs) {
  if (threadIdx.x == 0 && blockIdx.x == 0) {
    int run = 0;
    for (int e = 0; e < NEXP; ++e) { offs[e] = run; run += counts[e]; }
  }
}

// ffn1: Hmat[row, h] = silu(x@W1[e]^T) * (x@W2[e]^T), rows packed per expert.
// tile: BM=128 tokens x BN=64 h-cols x BK=32, 4 waves (2x2), dual accumulators.
__global__ __launch_bounds__(256) void ffn1_kernel(const short* __restrict__ xbf,
    const float* __restrict__ W1, const float* __restrict__ W2,
    const int* __restrict__ counts, const int* __restrict__ offs,
    const int* __restrict__ tlist, short* __restrict__ hmat) {
  int e = blockIdx.z;
  int cnt = counts[e];
  int m0 = blockIdx.y * 128;
  if (m0 >= cnt) return;
  int n0 = blockIdx.x * 64;
  __shared__ __attribute__((aligned(16))) short As[128 * 40];
  __shared__ __attribute__((aligned(16))) short Bs1[64 * 40];
  __shared__ __attribute__((aligned(16))) short Bs2[64 * 40];
  __shared__ int toks[128];
  int tid = threadIdx.x;
  if (tid < 128) {
    int m = m0 + tid;
    toks[tid] = tlist[e * T_TOK + (m < cnt ? m : cnt - 1)];
  }
  __syncthreads();
  const float* W1e = W1 + (size_t)e * HDIM * DDIM + (size_t)n0 * DDIM;
  const float* W2e = W2 + (size_t)e * HDIM * DDIM + (size_t)n0 * DDIM;
  int lane = tid & 63, wid = tid >> 6;
  int wr = wid >> 1, wc = wid & 1;
  int lrow = lane & 15, lq = lane >> 4;
  floatx4 accg[4][2], accu[4][2];
#pragma unroll
  for (int i = 0; i < 4; ++i)
#pragma unroll
    for (int j = 0; j < 2; ++j) {
      accg[i][j] = (floatx4){0.f, 0.f, 0.f, 0.f};
      accu[i][j] = (floatx4){0.f, 0.f, 0.f, 0.f};
    }
  int ar0 = tid >> 2, ac0 = (tid & 3) * 8;   // A: 2 chunks, rows ar0, ar0+64
  int br0 = tid >> 3, bc0 = (tid & 7) * 4;   // B: 2 chunks, rows br0, br0+32
  int tokA0 = toks[ar0], tokA1 = toks[ar0 + 64];
  const short* xA0 = xbf + (size_t)tokA0 * DDIM + ac0;
  const short* xA1 = xbf + (size_t)tokA1 * DDIM + ac0;
  const float* pB1a = W1e + (size_t)br0 * DDIM + bc0;
  const float* pB1b = W1e + (size_t)(br0 + 32) * DDIM + bc0;
  const float* pB2a = W2e + (size_t)br0 * DDIM + bc0;
  const float* pB2b = W2e + (size_t)(br0 + 32) * DDIM + bc0;

  for (int kk = 0; kk < DDIM; kk += 32) {
    *(short8*)&As[ar0 * 40 + ac0]        = *(const short8*)(xA0 + kk);
    *(short8*)&As[(ar0 + 64) * 40 + ac0] = *(const short8*)(xA1 + kk);
    {
      float4 v1a = *(const float4*)(pB1a + kk);
      float4 v1b = *(const float4*)(pB1b + kk);
      float4 v2a = *(const float4*)(pB2a + kk);
      float4 v2b = *(const float4*)(pB2b + kk);
      *(short4v*)&Bs1[br0 * 40 + bc0]        = (short4v){f2bf(v1a.x), f2bf(v1a.y), f2bf(v1a.z), f2bf(v1a.w)};
      *(short4v*)&Bs1[(br0 + 32) * 40 + bc0] = (short4v){f2bf(v1b.x), f2bf(v1b.y), f2bf(v1b.z), f2bf(v1b.w)};
      *(short4v*)&Bs2[br0 * 40 + bc0]        = (short4v){f2bf(v2a.x), f2bf(v2a.y), f2bf(v2a.z), f2bf(v2a.w)};
      *(short4v*)&Bs2[(br0 + 32) * 40 + bc0] = (short4v){f2bf(v2b.x), f2bf(v2b.y), f2bf(v2b.z), f2bf(v2b.w)};
    }
    __syncthreads();
    short8 a[4], b1[2], b2[2];
#pragma unroll
    for (int mf = 0; mf < 4; ++mf)
      a[mf] = *(short8*)&As[(wr * 64 + mf * 16 + lrow) * 40 + lq * 8];
#pragma unroll
    for (int nf = 0; nf < 2; ++nf) {
      b1[nf] = *(short8*)&Bs1[(wc * 32 + nf * 16 + lrow) * 40 + lq * 8];
      b2[nf] = *(short8*)&Bs2[(wc * 32 + nf * 16 + lrow) * 40 + lq * 8];
    }
#pragma unroll
    for (int mf = 0; mf < 4; ++mf)
#pragma unroll
      for (int nf = 0; nf < 2; ++nf) {
        accg[mf][nf] = __builtin_amdgcn_mfma_f32_16x16x32_bf16(a[mf], b1[nf], accg[mf][nf], 0, 0, 0);
        accu[mf][nf] = __builtin_amdgcn_mfma_f32_16x16x32_bf16(a[mf], b2[nf], accu[mf][nf], 0, 0, 0);
      }
    __syncthreads();
  }
  int base = offs[e];
#pragma unroll
  for (int mf = 0; mf < 4; ++mf)
#pragma unroll
    for (int r = 0; r < 4; ++r) {
      int mloc = wr * 64 + mf * 16 + lq * 4 + r;
      if (m0 + mloc < cnt) {
        size_t row = (size_t)(base + m0 + mloc);
#pragma unroll
        for (int nf = 0; nf < 2; ++nf) {
          float g = accg[mf][nf][r];
          float u = accu[mf][nf][r];
          float h = g / (1.f + __expf(-g)) * u;
          hmat[row * HDIM + n0 + wc * 32 + nf * 16 + lrow] = f2bf(h);
        }
      }
    }
}

// ffn2: out[t, :] += w * (Hmat_row @ W3[e]^T). tile 128x128xK32, atomicAdd epilogue.
__global__ __launch_bounds__(256) void ffn2_kernel(const short* __restrict__ hmat,
    const float* __restrict__ W3,
    const int* __restrict__ counts, const int* __restrict__ offs,
    const int* __restrict__ tlist, const float* __restrict__ wlist,
    float* __restrict__ out) {
  int e = blockIdx.z;
  int cnt = counts[e];
  int m0 = blockIdx.y * 128;
  if (m0 >= cnt) return;
  int n0 = blockIdx.x * 128;
  __shared__ __attribute__((aligned(16))) short As[128 * 40];
  __shared__ __attribute__((aligned(16))) short Bs[128 * 40];
  __shared__ int toks[128];
  __shared__ float wts[128];
  int tid = threadIdx.x;
  if (tid < 128) {
    int m = m0 + tid;
    int mc = m < cnt ? m : cnt - 1;
    toks[tid] = tlist[e * T_TOK + mc];
    wts[tid] = (m < cnt) ? wlist[e * T_TOK + m] : 0.f;
  }
  __syncthreads();
  int base = offs[e];
  const float* W3e = W3 + (size_t)e * DDIM * HDIM + (size_t)n0 * HDIM;
  int lane = tid & 63, wid = tid >> 6;
  int wr = wid >> 1, wc = wid & 1;
  int lrow = lane & 15, lq = lane >> 4;
  floatx4 acc[4][4];
#pragma unroll
  for (int i = 0; i < 4; ++i)
#pragma unroll
    for (int j = 0; j < 4; ++j) acc[i][j] = (floatx4){0.f, 0.f, 0.f, 0.f};
  int ar0 = tid >> 2, ac0 = (tid & 3) * 8;
  int br0 = tid >> 3, bc0 = (tid & 7) * 4;
  int mA0 = m0 + ar0;       mA0 = mA0 < cnt ? mA0 : cnt - 1;
  int mA1 = m0 + ar0 + 64;  mA1 = mA1 < cnt ? mA1 : cnt - 1;
  const short* hA0 = hmat + (size_t)(base + mA0) * HDIM + ac0;
  const short* hA1 = hmat + (size_t)(base + mA1) * HDIM + ac0;

  for (int kk = 0; kk < HDIM; kk += 32) {
    *(short8*)&As[ar0 * 40 + ac0]        = *(const short8*)(hA0 + kk);
    *(short8*)&As[(ar0 + 64) * 40 + ac0] = *(const short8*)(hA1 + kk);
#pragma unroll
    for (int l = 0; l < 4; ++l) {
      int r = br0 + l * 32;
      float4 v = *(const float4*)(W3e + (size_t)r * HDIM + kk + bc0);
      *(short4v*)&Bs[r * 40 + bc0] = (short4v){f2bf(v.x), f2bf(v.y), f2bf(v.z), f2bf(v.w)};
    }
    __syncthreads();
    short8 a[4], b[4];
#pragma unroll
    for (int mf = 0; mf < 4; ++mf)
      a[mf] = *(short8*)&As[(wr * 64 + mf * 16 + lrow) * 40 + lq * 8];
#pragma unroll
    for (int nf = 0; nf < 4; ++nf)
      b[nf] = *(short8*)&Bs[(wc * 64 + nf * 16 + lrow) * 40 + lq * 8];
#pragma unroll
    for (int mf = 0; mf < 4; ++mf)
#pragma unroll
      for (int nf = 0; nf < 4; ++nf)
        acc[mf][nf] = __builtin_amdgcn_mfma_f32_16x16x32_bf16(a[mf], b[nf], acc[mf][nf], 0, 0, 0);
    __syncthreads();
  }
#pragma unroll
  for (int mf = 0; mf < 4; ++mf)
#pragma unroll
    for (int r = 0; r < 4; ++r) {
      int mloc = wr * 64 + mf * 16 + lq * 4 + r;
      if (m0 + mloc < cnt) {
        int t = toks[mloc];
        float w = wts[mloc];
        float* orow = out + (size_t)t * DDIM + n0 + wc * 64 + lrow;
#pragma unroll
        for (int nf = 0; nf < 4; ++nf)
          atomicAdd(orow + nf * 16, w * acc[mf][nf][r]);
      }
    }
}

extern "C" void kernel_launch(void* const* d_in, const int* in_sizes, int n_in,
                              void* d_out, int out_size, void* d_ws, size_t ws_size,
                              hipStream_t stream) {
  const float* x  = (const float*)d_in[0];
  const float* Wg = (const float*)d_in[1];
  const float* W1 = (const float*)d_in[2];
  const float* W2 = (const float*)d_in[3];
  const float* W3 = (const float*)d_in[4];
  float* out = (float*)d_out;
  char* ws = (char*)d_ws;
  int*   counts = (int*)(ws + 0);
  int*   offs   = (int*)(ws + 256);
  int*   tlist  = (int*)(ws + 512);
  float* wlist  = (float*)(ws + 512 + 131072);
  short* xbf    = (short*)(ws + 512 + 2 * 131072);
  short* hmat   = (short*)(ws + 8651264);

  zero_kernel<<<4096, 256, 0, stream>>>((float4*)out, counts);
  gating_kernel<<<4096, 64, 0, stream>>>(x, Wg, xbf, counts, tlist, wlist);
  offsets_kernel<<<1, 64, 0, stream>>>(counts, offs);
  ffn1_kernel<<<dim3(HDIM / 64, T_TOK / 128, NEXP), 256, 0, stream>>>(xbf, W1, W2, counts, offs, tlist, hmat);
  ffn2_kernel<<<dim3(DDIM / 128, T_TOK / 128, NEXP), 256, 0, stream>>>(hmat, W3, counts, offs, tlist, wlist, out);
}

// Round 2
// 640.500 us; speedup vs baseline: 1.0205x; 1.0205x over previous
//
#include <hip/hip_runtime.h>
#include <hip/hip_bf16.h>
#include <stdint.h>

// MoE FFN top-2 sparse, bf16 MFMA, global_load_lds staging. T=4096, D=1024, H=2816, E=8.
//
// FAST ws layout (needs 193,167,872 B):
//   [0]         counts[8]
//   [256]       offs[8]
//   [512]       tlist[E*T] int        131072
//   [131584]    re[2T] int            32768   (expert per token slot)
//   [164352]    rs[2T] int            32768   (slot within expert list)
//   [197120]    rw[2T] float          32768   (gate weight)
//   [229888]    xbf[T*D] bf16         8388608
//   [8618496]   hmat[8192*H] bf16     46137344
//   [54755840]  W3bf bf16             46137344
//   [100893184] W1bf bf16             46137344   <-- ypart[8192*D] fp32 (33.5MB) aliases here after ffn1
//   [147030528] W2bf bf16             46137344
// LEGACY layout (round-1, 54.8 MB) used if ws_size is too small.

#define T_TOK 4096
#define DDIM 1024
#define HDIM 2816
#define NEXP 8

typedef __attribute__((ext_vector_type(8))) short short8;
typedef __attribute__((ext_vector_type(4))) short short4v;
typedef __attribute__((ext_vector_type(4))) float floatx4;

__device__ __forceinline__ short f2bf(float f) {
  union { float f; unsigned int u; } v; v.f = f;
  unsigned int u = v.u;
  u += 0x7FFFu + ((u >> 16) & 1u);   // round-to-nearest-even
  return (short)(u >> 16);
}

// async global->LDS, 16B per lane. LDS dest = wave-uniform base + lane*16.
__device__ __forceinline__ void gl2lds16(const void* g, void* l) {
  __builtin_amdgcn_global_load_lds(
      (const __attribute__((address_space(1))) void*)g,
      (__attribute__((address_space(3))) void*)l, 16, 0, 0);
}

// ---------------------------------------------------------------- shared ----

__global__ void offsets_kernel(const int* __restrict__ counts, int* __restrict__ offs) {
  if (threadIdx.x == 0 && blockIdx.x == 0) {
    int run = 0;
    for (int e = 0; e < NEXP; ++e) { offs[e] = run; run += counts[e]; }
  }
}

// ------------------------------------------------------------- fast path ----

__global__ __launch_bounds__(64) void zero_counts_kernel(int* __restrict__ counts) {
  if (threadIdx.x < NEXP) counts[threadIdx.x] = 0;
}

// fp32 -> bf16 weight conversion, memory-bound. grid (11264, 3): z picks W1/W2/W3.
__global__ __launch_bounds__(256) void convert_kernel(
    const float* __restrict__ W1, const float* __restrict__ W2, const float* __restrict__ W3,
    short* __restrict__ W1bf, short* __restrict__ W2bf, short* __restrict__ W3bf) {
  int z = blockIdx.y;
  const float* src = (z == 0) ? W1 : (z == 1) ? W2 : W3;
  short* dst = (z == 0) ? W1bf : (z == 1) ? W2bf : W3bf;
  size_t i = ((size_t)blockIdx.x * 256 + threadIdx.x) * 8;
  float4 v0 = *(const float4*)(src + i);
  float4 v1 = *(const float4*)(src + i + 4);
  short8 s = {f2bf(v0.x), f2bf(v0.y), f2bf(v0.z), f2bf(v0.w),
              f2bf(v1.x), f2bf(v1.y), f2bf(v1.z), f2bf(v1.w)};
  *(short8*)(dst + i) = s;
}

__global__ __launch_bounds__(64) void gating_fast_kernel(const float* __restrict__ x,
    const float* __restrict__ Wg, short* __restrict__ xbf,
    int* __restrict__ counts, int* __restrict__ tlist,
    int* __restrict__ re, int* __restrict__ rs, float* __restrict__ rw) {
  int t = blockIdx.x;
  int lane = threadIdx.x;
  const float* xt = x + (size_t)t * DDIM;
  float xr[16];
#pragma unroll
  for (int j = 0; j < 16; ++j) xr[j] = xt[j * 64 + lane];
  short* xbt = xbf + (size_t)t * DDIM;
#pragma unroll
  for (int j = 0; j < 16; ++j) xbt[j * 64 + lane] = f2bf(xr[j]);
  float s[NEXP];
#pragma unroll
  for (int e = 0; e < NEXP; ++e) {
    const float* wge = Wg + e * DDIM;
    float p = 0.f;
#pragma unroll
    for (int j = 0; j < 16; ++j) p += xr[j] * wge[j * 64 + lane];
#pragma unroll
    for (int o = 32; o > 0; o >>= 1) p += __shfl_xor(p, o, 64);
    s[e] = p;
  }
  if (lane == 0) {
    int e1 = 0; float s1 = s[0];
#pragma unroll
    for (int e = 1; e < NEXP; ++e) if (s[e] > s1) { s1 = s[e]; e1 = e; }
    int e2 = -1; float s2 = -1e30f;
#pragma unroll
    for (int e = 0; e < NEXP; ++e) if (e != e1 && s[e] > s2) { s2 = s[e]; e2 = e; }
    int slot = atomicAdd(&counts[e1], 1);
    tlist[e1 * T_TOK + slot] = t;
    re[2 * t] = e1; rs[2 * t] = slot; rw[2 * t] = s1;
    slot = atomicAdd(&counts[e2], 1);
    tlist[e2 * T_TOK + slot] = t;
    re[2 * t + 1] = e2; rs[2 * t + 1] = slot; rw[2 * t + 1] = s2;
  }
}

// ffn1: hmat[row, h] = silu(x@W1^T) * (x@W2^T). BM=128 x BN=64 x BK=32, 4 waves 2x2,
// dual accumulators, all staging via global_load_lds(16B), unpadded m97 LDS layout.
__global__ __launch_bounds__(256) void ffn1_fast_kernel(const short* __restrict__ xbf,
    const short* __restrict__ W1bf, const short* __restrict__ W2bf,
    const int* __restrict__ counts, const int* __restrict__ offs,
    const int* __restrict__ tlist, short* __restrict__ hmat) {
  int e = blockIdx.z;
  int cnt = counts[e];
  int m0 = blockIdx.y * 128;
  if (m0 >= cnt) return;
  int n0 = blockIdx.x * 64;
  __shared__ __attribute__((aligned(16))) short As[128 * 32];
  __shared__ __attribute__((aligned(16))) short Bs1[64 * 32];
  __shared__ __attribute__((aligned(16))) short Bs2[64 * 32];
  __shared__ int toks[128];
  int tid = threadIdx.x;
  if (tid < 128) {
    int m = m0 + tid;
    toks[tid] = tlist[e * T_TOK + (m < cnt ? m : cnt - 1)];
  }
  __syncthreads();
  int lane = tid & 63, w = tid >> 6;
  int wr = w >> 1, wc = w & 1;
  int lrow = lane & 15, lq = lane >> 4;
  int lr = lane >> 2;          // 0..15: row within a 16-row sweep
  int lc = (lane & 3) * 8;     // short offset within a 64B row
  // A: wave w stages rows w*32+lr and w*32+16+lr (gathered token rows)
  const short* pA0 = xbf + (size_t)toks[w * 32 + lr] * DDIM + lc;
  const short* pA1 = xbf + (size_t)toks[w * 32 + 16 + lr] * DDIM + lc;
  // B: wave w stages row w*16+lr of each 64-row weight tile
  const short* b1e = W1bf + (size_t)e * HDIM * DDIM;
  const short* b2e = W2bf + (size_t)e * HDIM * DDIM;
  const short* pB1 = b1e + (size_t)(n0 + w * 16 + lr) * DDIM + lc;
  const short* pB2 = b2e + (size_t)(n0 + w * 16 + lr) * DDIM + lc;
  void* lA0 = (void*)&As[(2 * w) * 512];
  void* lA1 = (void*)&As[(2 * w + 1) * 512];
  void* lB1 = (void*)&Bs1[w * 512];
  void* lB2 = (void*)&Bs2[w * 512];
  floatx4 accg[4][2], accu[4][2];
#pragma unroll
  for (int i = 0; i < 4; ++i)
#pragma unroll
    for (int j = 0; j < 2; ++j) {
      accg[i][j] = (floatx4){0.f, 0.f, 0.f, 0.f};
      accu[i][j] = (floatx4){0.f, 0.f, 0.f, 0.f};
    }
  for (int kk = 0; kk < DDIM; kk += 32) {
    gl2lds16(pA0, lA0);
    gl2lds16(pA1, lA1);
    gl2lds16(pB1, lB1);
    gl2lds16(pB2, lB2);
    pA0 += 32; pA1 += 32; pB1 += 32; pB2 += 32;
    __syncthreads();
    short8 a[4], b1[2], b2[2];
#pragma unroll
    for (int mf = 0; mf < 4; ++mf)
      a[mf] = *(short8*)&As[(wr * 64 + mf * 16 + lrow) * 32 + lq * 8];
#pragma unroll
    for (int nf = 0; nf < 2; ++nf) {
      b1[nf] = *(short8*)&Bs1[(wc * 32 + nf * 16 + lrow) * 32 + lq * 8];
      b2[nf] = *(short8*)&Bs2[(wc * 32 + nf * 16 + lrow) * 32 + lq * 8];
    }
#pragma unroll
    for (int mf = 0; mf < 4; ++mf)
#pragma unroll
      for (int nf = 0; nf < 2; ++nf) {
        accg[mf][nf] = __builtin_amdgcn_mfma_f32_16x16x32_bf16(a[mf], b1[nf], accg[mf][nf], 0, 0, 0);
        accu[mf][nf] = __builtin_amdgcn_mfma_f32_16x16x32_bf16(a[mf], b2[nf], accu[mf][nf], 0, 0, 0);
      }
    __syncthreads();
  }
  int base = offs[e];
#pragma unroll
  for (int mf = 0; mf < 4; ++mf)
#pragma unroll
    for (int r = 0; r < 4; ++r) {
      int mloc = wr * 64 + mf * 16 + lq * 4 + r;
      if (m0 + mloc < cnt) {
        size_t row = (size_t)(base + m0 + mloc);
#pragma unroll
        for (int nf = 0; nf < 2; ++nf) {
          float g = accg[mf][nf][r];
          float u = accu[mf][nf][r];
          float h = g / (1.f + __expf(-g)) * u;
          hmat[row * HDIM + n0 + wc * 32 + nf * 16 + lrow] = f2bf(h);
        }
      }
    }
}

// ffn2: ypart[row, :] = hmat_row @ W3^T (m97 128x128xK32 structure, plain stores).
__global__ __launch_bounds__(256) void ffn2_fast_kernel(const short* __restrict__ hmat,
    const short* __restrict__ W3bf,
    const int* __restrict__ counts, const int* __restrict__ offs,
    float* __restrict__ ypart) {
  int e = blockIdx.z;
  int cnt = counts[e];
  int m0 = blockIdx.y * 128;
  if (m0 >= cnt) return;
  int n0 = blockIdx.x * 128;
  int base = offs[e];
  __shared__ __attribute__((aligned(16))) short As[128 * 32];
  __shared__ __attribute__((aligned(16))) short Bs[128 * 32];
  int tid = threadIdx.x;
  int lane = tid & 63, w = tid >> 6;
  int wr = w >> 1, wc = w & 1;
  int lrow = lane & 15, lq = lane >> 4;
  int lr = lane >> 2;
  int lc = (lane & 3) * 8;
  int gA0 = m0 + w * 32 + lr;      gA0 = gA0 < cnt ? gA0 : cnt - 1;
  int gA1 = m0 + w * 32 + 16 + lr; gA1 = gA1 < cnt ? gA1 : cnt - 1;
  const short* pA0 = hmat + (size_t)(base + gA0) * HDIM + lc;
  const short* pA1 = hmat + (size_t)(base + gA1) * HDIM + lc;
  const short* W3e = W3bf + (size_t)e * DDIM * HDIM;
  const short* pB0 = W3e + (size_t)(n0 + w * 32 + lr) * HDIM + lc;
  const short* pB1 = W3e + (size_t)(n0 + w * 32 + 16 + lr) * HDIM + lc;
  void* lA0 = (void*)&As[(2 * w) * 512];
  void* lA1 = (void*)&As[(2 * w + 1) * 512];
  void* lB0 = (void*)&Bs[(2 * w) * 512];
  void* lB1 = (void*)&Bs[(2 * w + 1) * 512];
  floatx4 acc[4][4];
#pragma unroll
  for (int i = 0; i < 4; ++i)
#pragma unroll
    for (int j = 0; j < 4; ++j) acc[i][j] = (floatx4){0.f, 0.f, 0.f, 0.f};
  for (int kk = 0; kk < HDIM; kk += 32) {
    gl2lds16(pA0, lA0);
    gl2lds16(pA1, lA1);
    gl2lds16(pB0, lB0);
    gl2lds16(pB1, lB1);
    pA0 += 32; pA1 += 32; pB0 += 32; pB1 += 32;
    __syncthreads();
    short8 a[4], b[4];
#pragma unroll
    for (int mf = 0; mf < 4; ++mf)
      a[mf] = *(short8*)&As[(wr * 64 + mf * 16 + lrow) * 32 + lq * 8];
#pragma unroll
    for (int nf = 0; nf < 4; ++nf)
      b[nf] = *(short8*)&Bs[(wc * 64 + nf * 16 + lrow) * 32 + lq * 8];
#pragma unroll
    for (int mf = 0; mf < 4; ++mf)
#pragma unroll
      for (int nf = 0; nf < 4; ++nf)
        acc[mf][nf] = __builtin_amdgcn_mfma_f32_16x16x32_bf16(a[mf], b[nf], acc[mf][nf], 0, 0, 0);
    __syncthreads();
  }
#pragma unroll
  for (int mf = 0; mf < 4; ++mf)
#pragma unroll
    for (int r = 0; r < 4; ++r) {
      int mloc = wr * 64 + mf * 16 + lq * 4 + r;
      if (m0 + mloc < cnt) {
        float* orow = ypart + (size_t)(base + m0 + mloc) * DDIM + n0 + wc * 64 + lrow;
#pragma unroll
        for (int nf = 0; nf < 4; ++nf)
          orow[nf * 16] = acc[mf][nf][r];
      }
    }
}

// out[t,:] = w0*ypart[r0,:] + w1*ypart[r1,:]  (fully overwrites out; no atomics)
__global__ __launch_bounds__(256) void combine_kernel(const float4* __restrict__ ypart4,
    const int* __restrict__ offs, const int* __restrict__ re, const int* __restrict__ rs,
    const float* __restrict__ rw, float4* __restrict__ out4) {
  int t = blockIdx.x;
  int i = threadIdx.x;
  int r0 = offs[re[2 * t]] + rs[2 * t];
  int r1 = offs[re[2 * t + 1]] + rs[2 * t + 1];
  float w0 = rw[2 * t], w1 = rw[2 * t + 1];
  float4 a = ypart4[(size_t)r0 * 256 + i];
  float4 b = ypart4[(size_t)r1 * 256 + i];
  out4[(size_t)t * 256 + i] = make_float4(w0 * a.x + w1 * b.x, w0 * a.y + w1 * b.y,
                                          w0 * a.z + w1 * b.z, w0 * a.w + w1 * b.w);
}

// ----------------------------------------------------------- legacy path ----
// round-1 kernels, used only if ws_size is too small for the fast layout.

__global__ __launch_bounds__(256) void zero_kernel(float4* __restrict__ out4, int* __restrict__ counts) {
  int i = blockIdx.x * 256 + threadIdx.x;
  out4[i] = make_float4(0.f, 0.f, 0.f, 0.f);
  if (blockIdx.x == 0 && threadIdx.x < NEXP) counts[threadIdx.x] = 0;
}

__global__ __launch_bounds__(64) void gating_kernel(const float* __restrict__ x,
    const float* __restrict__ Wg, short* __restrict__ xbf,
    int* __restrict__ counts, int* __restrict__ tlist, float* __restrict__ wlist) {
  int t = blockIdx.x;
  int lane = threadIdx.x;
  const float* xt = x + (size_t)t * DDIM;
  float xr[16];
#pragma unroll
  for (int j = 0; j < 16; ++j) xr[j] = xt[j * 64 + lane];
  short* xbt = xbf + (size_t)t * DDIM;
#pragma unroll
  for (int j = 0; j < 16; ++j) xbt[j * 64 + lane] = f2bf(xr[j]);
  float s[NEXP];
#pragma unroll
  for (int e = 0; e < NEXP; ++e) {
    const float* wge = Wg + e * DDIM;
    float p = 0.f;
#pragma unroll
    for (int j = 0; j < 16; ++j) p += xr[j] * wge[j * 64 + lane];
#pragma unroll
    for (int o = 32; o > 0; o >>= 1) p += __shfl_xor(p, o, 64);
    s[e] = p;
  }
  if (lane == 0) {
    int e1 = 0; float s1 = s[0];
#pragma unroll
    for (int e = 1; e < NEXP; ++e) if (s[e] > s1) { s1 = s[e]; e1 = e; }
    int e2 = -1; float s2 = -1e30f;
#pragma unroll
    for (int e = 0; e < NEXP; ++e) if (e != e1 && s[e] > s2) { s2 = s[e]; e2 = e; }
    int slot = atomicAdd(&counts[e1], 1);
    tlist[e1 * T_TOK + slot] = t; wlist[e1 * T_TOK + slot] = s1;
    slot = atomicAdd(&counts[e2], 1);
    tlist[e2 * T_TOK + slot] = t; wlist[e2 * T_TOK + slot] = s2;
  }
}

__global__ __launch_bounds__(256) void ffn1_kernel(const short* __restrict__ xbf,
    const float* __restrict__ W1, const float* __restrict__ W2,
    const int* __restrict__ counts, const int* __restrict__ offs,
    const int* __restrict__ tlist, short* __restrict__ hmat) {
  int e = blockIdx.z;
  int cnt = counts[e];
  int m0 = blockIdx.y * 128;
  if (m0 >= cnt) return;
  int n0 = blockIdx.x * 64;
  __shared__ __attribute__((aligned(16))) short As[128 * 40];
  __shared__ __attribute__((aligned(16))) short Bs1[64 * 40];
  __shared__ __attribute__((aligned(16))) short Bs2[64 * 40];
  __shared__ int toks[128];
  int tid = threadIdx.x;
  if (tid < 128) {
    int m = m0 + tid;
    toks[tid] = tlist[e * T_TOK + (m < cnt ? m : cnt - 1)];
  }
  __syncthreads();
  const float* W1e = W1 + (size_t)e * HDIM * DDIM + (size_t)n0 * DDIM;
  const float* W2e = W2 + (size_t)e * HDIM * DDIM + (size_t)n0 * DDIM;
  int lane = tid & 63, wid = tid >> 6;
  int wr = wid >> 1, wc = wid & 1;
  int lrow = lane & 15, lq = lane >> 4;
  floatx4 accg[4][2], accu[4][2];
#pragma unroll
  for (int i = 0; i < 4; ++i)
#pragma unroll
    for (int j = 0; j < 2; ++j) {
      accg[i][j] = (floatx4){0.f, 0.f, 0.f, 0.f};
      accu[i][j] = (floatx4){0.f, 0.f, 0.f, 0.f};
    }
  int ar0 = tid >> 2, ac0 = (tid & 3) * 8;
  int br0 = tid >> 3, bc0 = (tid & 7) * 4;
  int tokA0 = toks[ar0], tokA1 = toks[ar0 + 64];
  const short* xA0 = xbf + (size_t)tokA0 * DDIM + ac0;
  const short* xA1 = xbf + (size_t)tokA1 * DDIM + ac0;
  const float* pB1a = W1e + (size_t)br0 * DDIM + bc0;
  const float* pB1b = W1e + (size_t)(br0 + 32) * DDIM + bc0;
  const float* pB2a = W2e + (size_t)br0 * DDIM + bc0;
  const float* pB2b = W2e + (size_t)(br0 + 32) * DDIM + bc0;

  for (int kk = 0; kk < DDIM; kk += 32) {
    *(short8*)&As[ar0 * 40 + ac0]        = *(const short8*)(xA0 + kk);
    *(short8*)&As[(ar0 + 64) * 40 + ac0] = *(const short8*)(xA1 + kk);
    {
      float4 v1a = *(const float4*)(pB1a + kk);
      float4 v1b = *(const float4*)(pB1b + kk);
      float4 v2a = *(const float4*)(pB2a + kk);
      float4 v2b = *(const float4*)(pB2b + kk);
      *(short4v*)&Bs1[br0 * 40 + bc0]        = (short4v){f2bf(v1a.x), f2bf(v1a.y), f2bf(v1a.z), f2bf(v1a.w)};
      *(short4v*)&Bs1[(br0 + 32) * 40 + bc0] = (short4v){f2bf(v1b.x), f2bf(v1b.y), f2bf(v1b.z), f2bf(v1b.w)};
      *(short4v*)&Bs2[br0 * 40 + bc0]        = (short4v){f2bf(v2a.x), f2bf(v2a.y), f2bf(v2a.z), f2bf(v2a.w)};
      *(short4v*)&Bs2[(br0 + 32) * 40 + bc0] = (short4v){f2bf(v2b.x), f2bf(v2b.y), f2bf(v2b.z), f2bf(v2b.w)};
    }
    __syncthreads();
    short8 a[4], b1[2], b2[2];
#pragma unroll
    for (int mf = 0; mf < 4; ++mf)
      a[mf] = *(short8*)&As[(wr * 64 + mf * 16 + lrow) * 40 + lq * 8];
#pragma unroll
    for (int nf = 0; nf < 2; ++nf) {
      b1[nf] = *(short8*)&Bs1[(wc * 32 + nf * 16 + lrow) * 40 + lq * 8];
      b2[nf] = *(short8*)&Bs2[(wc * 32 + nf * 16 + lrow) * 40 + lq * 8];
    }
#pragma unroll
    for (int mf = 0; mf < 4; ++mf)
#pragma unroll
      for (int nf = 0; nf < 2; ++nf) {
        accg[mf][nf] = __builtin_amdgcn_mfma_f32_16x16x32_bf16(a[mf], b1[nf], accg[mf][nf], 0, 0, 0);
        accu[mf][nf] = __builtin_amdgcn_mfma_f32_16x16x32_bf16(a[mf], b2[nf], accu[mf][nf], 0, 0, 0);
      }
    __syncthreads();
  }
  int base = offs[e];
#pragma unroll
  for (int mf = 0; mf < 4; ++mf)
#pragma unroll
    for (int r = 0; r < 4; ++r) {
      int mloc = wr * 64 + mf * 16 + lq * 4 + r;
      if (m0 + mloc < cnt) {
        size_t row = (size_t)(base + m0 + mloc);
#pragma unroll
        for (int nf = 0; nf < 2; ++nf) {
          float g = accg[mf][nf][r];
          float u = accu[mf][nf][r];
          float h = g / (1.f + __expf(-g)) * u;
          hmat[row * HDIM + n0 + wc * 32 + nf * 16 + lrow] = f2bf(h);
        }
      }
    }
}

__global__ __launch_bounds__(256) void ffn2_kernel(const short* __restrict__ hmat,
    const float* __restrict__ W3,
    const int* __restrict__ counts, const int* __restrict__ offs,
    const int* __restrict__ tlist, const float* __restrict__ wlist,
    float* __restrict__ out) {
  int e = blockIdx.z;
  int cnt = counts[e];
  int m0 = blockIdx.y * 128;
  if (m0 >= cnt) return;
  int n0 = blockIdx.x * 128;
  __shared__ __attribute__((aligned(16))) short As[128 * 40];
  __shared__ __attribute__((aligned(16))) short Bs[128 * 40];
  __shared__ int toks[128];
  __shared__ float wts[128];
  int tid = threadIdx.x;
  if (tid < 128) {
    int m = m0 + tid;
    int mc = m < cnt ? m : cnt - 1;
    toks[tid] = tlist[e * T_TOK + mc];
    wts[tid] = (m < cnt) ? wlist[e * T_TOK + m] : 0.f;
  }
  __syncthreads();
  int base = offs[e];
  const float* W3e = W3 + (size_t)e * DDIM * HDIM + (size_t)n0 * HDIM;
  int lane = tid & 63, wid = tid >> 6;
  int wr = wid >> 1, wc = wid & 1;
  int lrow = lane & 15, lq = lane >> 4;
  floatx4 acc[4][4];
#pragma unroll
  for (int i = 0; i < 4; ++i)
#pragma unroll
    for (int j = 0; j < 4; ++j) acc[i][j] = (floatx4){0.f, 0.f, 0.f, 0.f};
  int ar0 = tid >> 2, ac0 = (tid & 3) * 8;
  int br0 = tid >> 3, bc0 = (tid & 7) * 4;
  int mA0 = m0 + ar0;       mA0 = mA0 < cnt ? mA0 : cnt - 1;
  int mA1 = m0 + ar0 + 64;  mA1 = mA1 < cnt ? mA1 : cnt - 1;
  const short* hA0 = hmat + (size_t)(base + mA0) * HDIM + ac0;
  const short* hA1 = hmat + (size_t)(base + mA1) * HDIM + ac0;

  for (int kk = 0; kk < HDIM; kk += 32) {
    *(short8*)&As[ar0 * 40 + ac0]        = *(const short8*)(hA0 + kk);
    *(short8*)&As[(ar0 + 64) * 40 + ac0] = *(const short8*)(hA1 + kk);
#pragma unroll
    for (int l = 0; l < 4; ++l) {
      int r = br0 + l * 32;
      float4 v = *(const float4*)(W3e + (size_t)r * HDIM + kk + bc0);
      *(short4v*)&Bs[r * 40 + bc0] = (short4v){f2bf(v.x), f2bf(v.y), f2bf(v.z), f2bf(v.w)};
    }
    __syncthreads();
    short8 a[4], b[4];
#pragma unroll
    for (int mf = 0; mf < 4; ++mf)
      a[mf] = *(short8*)&As[(wr * 64 + mf * 16 + lrow) * 40 + lq * 8];
#pragma unroll
    for (int nf = 0; nf < 4; ++nf)
      b[nf] = *(short8*)&Bs[(wc * 64 + nf * 16 + lrow) * 40 + lq * 8];
#pragma unroll
    for (int mf = 0; mf < 4; ++mf)
#pragma unroll
      for (int nf = 0; nf < 4; ++nf)
        acc[mf][nf] = __builtin_amdgcn_mfma_f32_16x16x32_bf16(a[mf], b[nf], acc[mf][nf], 0, 0, 0);
    __syncthreads();
  }
#pragma unroll
  for (int mf = 0; mf < 4; ++mf)
#pragma unroll
    for (int r = 0; r < 4; ++r) {
      int mloc = wr * 64 + mf * 16 + lq * 4 + r;
      if (m0 + mloc < cnt) {
        int t = toks[mloc];
        float w = wts[mloc];
        float* orow = out + (size_t)t * DDIM + n0 + wc * 64 + lrow;
#pragma unroll
        for (int nf = 0; nf < 4; ++nf)
          atomicAdd(orow + nf * 16, w * acc[mf][nf][r]);
      }
    }
}

// ---------------------------------------------------------------- launch ----

extern "C" void kernel_launch(void* const* d_in, const int* in_sizes, int n_in,
                              void* d_out, int out_size, void* d_ws, size_t ws_size,
                              hipStream_t stream) {
  const float* x  = (const float*)d_in[0];
  const float* Wg = (const float*)d_in[1];
  const float* W1 = (const float*)d_in[2];
  const float* W2 = (const float*)d_in[3];
  const float* W3 = (const float*)d_in[4];
  float* out = (float*)d_out;
  char* ws = (char*)d_ws;

  const size_t NEED_FAST = 193167872ull;
  if (ws_size >= NEED_FAST) {
    int*   counts = (int*)(ws + 0);
    int*   offs   = (int*)(ws + 256);
    int*   tlist  = (int*)(ws + 512);
    int*   re     = (int*)(ws + 131584);
    int*   rs     = (int*)(ws + 164352);
    float* rw     = (float*)(ws + 197120);
    short* xbf    = (short*)(ws + 229888);
    short* hmat   = (short*)(ws + 8618496);
    short* W3bf   = (short*)(ws + 54755840);
    short* W1bf   = (short*)(ws + 100893184);
    short* W2bf   = (short*)(ws + 147030528);
    float* ypart  = (float*)(ws + 100893184);   // aliases W1bf (dead after ffn1)

    zero_counts_kernel<<<1, 64, 0, stream>>>(counts);
    convert_kernel<<<dim3(11264, 3), 256, 0, stream>>>(W1, W2, W3, W1bf, W2bf, W3bf);
    gating_fast_kernel<<<T_TOK, 64, 0, stream>>>(x, Wg, xbf, counts, tlist, re, rs, rw);
    offsets_kernel<<<1, 64, 0, stream>>>(counts, offs);
    ffn1_fast_kernel<<<dim3(HDIM / 64, T_TOK / 128, NEXP), 256, 0, stream>>>(
        xbf, W1bf, W2bf, counts, offs, tlist, hmat);
    ffn2_fast_kernel<<<dim3(DDIM / 128, T_TOK / 128, NEXP), 256, 0, stream>>>(
        hmat, W3bf, counts, offs, ypart);
    combine_kernel<<<T_TOK, 256, 0, stream>>>((const float4*)ypart, offs, re, rs, rw, (float4*)out);
  } else {
    // legacy round-1 path (52.3 MB ws)
    int*   counts = (int*)(ws + 0);
    int*   offs   = (int*)(ws + 256);
    int*   tlist  = (int*)(ws + 512);
    float* wlist  = (float*)(ws + 512 + 131072);
    short* xbf    = (short*)(ws + 512 + 2 * 131072);
    short* hmat   = (short*)(ws + 8651264);

    zero_kernel<<<4096, 256, 0, stream>>>((float4*)out, counts);
    gating_kernel<<<4096, 64, 0, stream>>>(x, Wg, xbf, counts, tlist, wlist);
    offsets_kernel<<<1, 64, 0, stream>>>(counts, offs);
    ffn1_kernel<<<dim3(HDIM / 64, T_TOK / 128, NEXP), 256, 0, stream>>>(xbf, W1, W2, counts, offs, tlist, hmat);
    ffn2_kernel<<<dim3(DDIM / 128, T_TOK / 128, NEXP), 256, 0, stream>>>(hmat, W3, counts, offs, tlist, wlist, out);
  }
}

// Round 3
// 622.171 us; speedup vs baseline: 1.0506x; 1.0295x over previous
//
#include <hip/hip_runtime.h>
#include <hip/hip_bf16.h>
#include <stdint.h>

// MoE FFN top-2 sparse, bf16 MFMA, global_load_lds staging. T=4096, D=1024, H=2816, E=8.
//
// ws layout (needs 193,167,872 B; round-2 confirmed ws_size is sufficient):
//   [0]         counts[8]
//   [256]       offs[8]
//   [512]       tlist[E*T] int        131072
//   [131584]    re[2T] int            32768   (expert per token slot)
//   [164352]    rs[2T] int            32768   (slot within expert list)
//   [197120]    rw[2T] float          32768   (gate weight)
//   [229888]    xbf[T*D] bf16         8388608
//   [8618496]   hmat[8192*H] bf16     46137344
//   [54755840]  W3bf bf16             46137344
//   [100893184] W1bf bf16             46137344   <-- ypart0[8192*D] fp32 aliases after ffn1
//   [147030528] W2bf bf16             46137344   <-- ypart1[8192*D] fp32 aliases after ffn1

#define T_TOK 4096
#define DDIM 1024
#define HDIM 2816
#define NEXP 8

typedef __attribute__((ext_vector_type(8))) short short8;
typedef __attribute__((ext_vector_type(4))) short short4v;
typedef __attribute__((ext_vector_type(4))) float floatx4;

__device__ __forceinline__ short f2bf(float f) {
  union { float f; unsigned int u; } v; v.f = f;
  unsigned int u = v.u;
  u += 0x7FFFu + ((u >> 16) & 1u);   // round-to-nearest-even
  return (short)(u >> 16);
}

// async global->LDS, 16B per lane. LDS dest = wave-uniform base + lane*16.
__device__ __forceinline__ void gl2lds16(const void* g, void* l) {
  __builtin_amdgcn_global_load_lds(
      (const __attribute__((address_space(1))) void*)g,
      (__attribute__((address_space(3))) void*)l, 16, 0, 0);
}

__global__ void offsets_kernel(const int* __restrict__ counts, int* __restrict__ offs) {
  if (threadIdx.x == 0 && blockIdx.x == 0) {
    int run = 0;
    for (int e = 0; e < NEXP; ++e) { offs[e] = run; run += counts[e]; }
  }
}

// fp32 -> bf16 weight conversion. Perfectly coalesced: 16B/lane float4 read,
// 8B/lane short4 write, grid-stride. blockIdx.y picks W1/W2/W3.
// Also zeroes counts (runs before gating in stream order).
#define CONV_ELEM4 5767168   // (8*2816*1024)/4 float4s per matrix
__global__ __launch_bounds__(256) void convert_kernel(
    const float* __restrict__ W1, const float* __restrict__ W2, const float* __restrict__ W3,
    short* __restrict__ W1bf, short* __restrict__ W2bf, short* __restrict__ W3bf,
    int* __restrict__ counts) {
  if (blockIdx.x == 0 && blockIdx.y == 0 && threadIdx.x < NEXP) counts[threadIdx.x] = 0;
  int z = blockIdx.y;
  const float4* src = (const float4*)((z == 0) ? W1 : (z == 1) ? W2 : W3);
  short4v* dst = (short4v*)((z == 0) ? W1bf : (z == 1) ? W2bf : W3bf);
  size_t stride = (size_t)gridDim.x * 256;
  for (size_t i = (size_t)blockIdx.x * 256 + threadIdx.x; i < CONV_ELEM4; i += stride) {
    float4 v = src[i];
    dst[i] = (short4v){f2bf(v.x), f2bf(v.y), f2bf(v.z), f2bf(v.w)};
  }
}

__global__ __launch_bounds__(64) void gating_fast_kernel(const float* __restrict__ x,
    const float* __restrict__ Wg, short* __restrict__ xbf,
    int* __restrict__ counts, int* __restrict__ tlist,
    int* __restrict__ re, int* __restrict__ rs, float* __restrict__ rw) {
  int t = blockIdx.x;
  int lane = threadIdx.x;
  const float* xt = x + (size_t)t * DDIM;
  float xr[16];
#pragma unroll
  for (int j = 0; j < 16; ++j) xr[j] = xt[j * 64 + lane];
  short* xbt = xbf + (size_t)t * DDIM;
#pragma unroll
  for (int j = 0; j < 16; ++j) xbt[j * 64 + lane] = f2bf(xr[j]);
  float s[NEXP];
#pragma unroll
  for (int e = 0; e < NEXP; ++e) {
    const float* wge = Wg + e * DDIM;
    float p = 0.f;
#pragma unroll
    for (int j = 0; j < 16; ++j) p += xr[j] * wge[j * 64 + lane];
#pragma unroll
    for (int o = 32; o > 0; o >>= 1) p += __shfl_xor(p, o, 64);
    s[e] = p;
  }
  if (lane == 0) {
    int e1 = 0; float s1 = s[0];
#pragma unroll
    for (int e = 1; e < NEXP; ++e) if (s[e] > s1) { s1 = s[e]; e1 = e; }
    int e2 = -1; float s2 = -1e30f;
#pragma unroll
    for (int e = 0; e < NEXP; ++e) if (e != e1 && s[e] > s2) { s2 = s[e]; e2 = e; }
    int slot = atomicAdd(&counts[e1], 1);
    tlist[e1 * T_TOK + slot] = t;
    re[2 * t] = e1; rs[2 * t] = slot; rw[2 * t] = s1;
    slot = atomicAdd(&counts[e2], 1);
    tlist[e2 * T_TOK + slot] = t;
    re[2 * t + 1] = e2; rs[2 * t + 1] = slot; rw[2 * t + 1] = s2;
  }
}

// ffn1: hmat[row, h] = silu(x@W1^T) * (x@W2^T). BM=128 x BN=64 x BK=32, 4 waves 2x2,
// dual accumulators, global_load_lds(16B) staging, unpadded m97 LDS layout.
__global__ __launch_bounds__(256) void ffn1_fast_kernel(const short* __restrict__ xbf,
    const short* __restrict__ W1bf, const short* __restrict__ W2bf,
    const int* __restrict__ counts, const int* __restrict__ offs,
    const int* __restrict__ tlist, short* __restrict__ hmat) {
  int e = blockIdx.z;
  int cnt = counts[e];
  int m0 = blockIdx.y * 128;
  if (m0 >= cnt) return;
  int n0 = blockIdx.x * 64;
  __shared__ __attribute__((aligned(16))) short As[128 * 32];
  __shared__ __attribute__((aligned(16))) short Bs1[64 * 32];
  __shared__ __attribute__((aligned(16))) short Bs2[64 * 32];
  __shared__ int toks[128];
  int tid = threadIdx.x;
  if (tid < 128) {
    int m = m0 + tid;
    toks[tid] = tlist[e * T_TOK + (m < cnt ? m : cnt - 1)];
  }
  __syncthreads();
  int lane = tid & 63, w = tid >> 6;
  int wr = w >> 1, wc = w & 1;
  int lrow = lane & 15, lq = lane >> 4;
  int lr = lane >> 2;          // 0..15: row within a 16-row sweep
  int lc = (lane & 3) * 8;     // short offset within a 64B row
  const short* pA0 = xbf + (size_t)toks[w * 32 + lr] * DDIM + lc;
  const short* pA1 = xbf + (size_t)toks[w * 32 + 16 + lr] * DDIM + lc;
  const short* b1e = W1bf + (size_t)e * HDIM * DDIM;
  const short* b2e = W2bf + (size_t)e * HDIM * DDIM;
  const short* pB1 = b1e + (size_t)(n0 + w * 16 + lr) * DDIM + lc;
  const short* pB2 = b2e + (size_t)(n0 + w * 16 + lr) * DDIM + lc;
  void* lA0 = (void*)&As[(2 * w) * 512];
  void* lA1 = (void*)&As[(2 * w + 1) * 512];
  void* lB1 = (void*)&Bs1[w * 512];
  void* lB2 = (void*)&Bs2[w * 512];
  floatx4 accg[4][2], accu[4][2];
#pragma unroll
  for (int i = 0; i < 4; ++i)
#pragma unroll
    for (int j = 0; j < 2; ++j) {
      accg[i][j] = (floatx4){0.f, 0.f, 0.f, 0.f};
      accu[i][j] = (floatx4){0.f, 0.f, 0.f, 0.f};
    }
  for (int kk = 0; kk < DDIM; kk += 32) {
    gl2lds16(pA0, lA0);
    gl2lds16(pA1, lA1);
    gl2lds16(pB1, lB1);
    gl2lds16(pB2, lB2);
    pA0 += 32; pA1 += 32; pB1 += 32; pB2 += 32;
    __syncthreads();
    short8 a[4], b1[2], b2[2];
#pragma unroll
    for (int mf = 0; mf < 4; ++mf)
      a[mf] = *(short8*)&As[(wr * 64 + mf * 16 + lrow) * 32 + lq * 8];
#pragma unroll
    for (int nf = 0; nf < 2; ++nf) {
      b1[nf] = *(short8*)&Bs1[(wc * 32 + nf * 16 + lrow) * 32 + lq * 8];
      b2[nf] = *(short8*)&Bs2[(wc * 32 + nf * 16 + lrow) * 32 + lq * 8];
    }
#pragma unroll
    for (int mf = 0; mf < 4; ++mf)
#pragma unroll
      for (int nf = 0; nf < 2; ++nf) {
        accg[mf][nf] = __builtin_amdgcn_mfma_f32_16x16x32_bf16(a[mf], b1[nf], accg[mf][nf], 0, 0, 0);
        accu[mf][nf] = __builtin_amdgcn_mfma_f32_16x16x32_bf16(a[mf], b2[nf], accu[mf][nf], 0, 0, 0);
      }
    __syncthreads();
  }
  int base = offs[e];
#pragma unroll
  for (int mf = 0; mf < 4; ++mf)
#pragma unroll
    for (int r = 0; r < 4; ++r) {
      int mloc = wr * 64 + mf * 16 + lq * 4 + r;
      if (m0 + mloc < cnt) {
        size_t row = (size_t)(base + m0 + mloc);
#pragma unroll
        for (int nf = 0; nf < 2; ++nf) {
          float g = accg[mf][nf][r];
          float u = accu[mf][nf][r];
          float h = g / (1.f + __expf(-g)) * u;
          hmat[row * HDIM + n0 + wc * 32 + nf * 16 + lrow] = f2bf(h);
        }
      }
    }
}

// ffn2: split-K x2. ypart[ks][row, :] = hmat_row[khalf] @ W3[khalf]^T.
// m97 128x128xK32 structure, plain stores, 1056 live blocks (~4/CU).
#define KSPLIT 2
#define KHALF (HDIM / KSPLIT)   // 1408
__global__ __launch_bounds__(256) void ffn2_fast_kernel(const short* __restrict__ hmat,
    const short* __restrict__ W3bf,
    const int* __restrict__ counts, const int* __restrict__ offs,
    float* __restrict__ ypart0, float* __restrict__ ypart1) {
  int e = blockIdx.z;
  int cnt = counts[e];
  int m0 = blockIdx.y * 128;
  if (m0 >= cnt) return;
  int ks = blockIdx.x >> 3;            // 0..1: K-split index
  int n0 = (blockIdx.x & 7) * 128;     // 0..7: n-tile
  int k0 = ks * KHALF;
  float* ypart = ks ? ypart1 : ypart0;
  int base = offs[e];
  __shared__ __attribute__((aligned(16))) short As[128 * 32];
  __shared__ __attribute__((aligned(16))) short Bs[128 * 32];
  int tid = threadIdx.x;
  int lane = tid & 63, w = tid >> 6;
  int wr = w >> 1, wc = w & 1;
  int lrow = lane & 15, lq = lane >> 4;
  int lr = lane >> 2;
  int lc = (lane & 3) * 8;
  int gA0 = m0 + w * 32 + lr;      gA0 = gA0 < cnt ? gA0 : cnt - 1;
  int gA1 = m0 + w * 32 + 16 + lr; gA1 = gA1 < cnt ? gA1 : cnt - 1;
  const short* pA0 = hmat + (size_t)(base + gA0) * HDIM + k0 + lc;
  const short* pA1 = hmat + (size_t)(base + gA1) * HDIM + k0 + lc;
  const short* W3e = W3bf + (size_t)e * DDIM * HDIM;
  const short* pB0 = W3e + (size_t)(n0 + w * 32 + lr) * HDIM + k0 + lc;
  const short* pB1 = W3e + (size_t)(n0 + w * 32 + 16 + lr) * HDIM + k0 + lc;
  void* lA0 = (void*)&As[(2 * w) * 512];
  void* lA1 = (void*)&As[(2 * w + 1) * 512];
  void* lB0 = (void*)&Bs[(2 * w) * 512];
  void* lB1 = (void*)&Bs[(2 * w + 1) * 512];
  floatx4 acc[4][4];
#pragma unroll
  for (int i = 0; i < 4; ++i)
#pragma unroll
    for (int j = 0; j < 4; ++j) acc[i][j] = (floatx4){0.f, 0.f, 0.f, 0.f};
  for (int kk = 0; kk < KHALF; kk += 32) {
    gl2lds16(pA0, lA0);
    gl2lds16(pA1, lA1);
    gl2lds16(pB0, lB0);
    gl2lds16(pB1, lB1);
    pA0 += 32; pA1 += 32; pB0 += 32; pB1 += 32;
    __syncthreads();
    short8 a[4], b[4];
#pragma unroll
    for (int mf = 0; mf < 4; ++mf)
      a[mf] = *(short8*)&As[(wr * 64 + mf * 16 + lrow) * 32 + lq * 8];
#pragma unroll
    for (int nf = 0; nf < 4; ++nf)
      b[nf] = *(short8*)&Bs[(wc * 64 + nf * 16 + lrow) * 32 + lq * 8];
#pragma unroll
    for (int mf = 0; mf < 4; ++mf)
#pragma unroll
      for (int nf = 0; nf < 4; ++nf)
        acc[mf][nf] = __builtin_amdgcn_mfma_f32_16x16x32_bf16(a[mf], b[nf], acc[mf][nf], 0, 0, 0);
    __syncthreads();
  }
#pragma unroll
  for (int mf = 0; mf < 4; ++mf)
#pragma unroll
    for (int r = 0; r < 4; ++r) {
      int mloc = wr * 64 + mf * 16 + lq * 4 + r;
      if (m0 + mloc < cnt) {
        float* orow = ypart + (size_t)(base + m0 + mloc) * DDIM + n0 + wc * 64 + lrow;
#pragma unroll
        for (int nf = 0; nf < 4; ++nf)
          orow[nf * 16] = acc[mf][nf][r];
      }
    }
}

// out[t,:] = w0*(y0[r0]+y1[r0]) + w1*(y0[r1]+y1[r1])  (overwrites out; no atomics)
__global__ __launch_bounds__(256) void combine_kernel(const float4* __restrict__ y0,
    const float4* __restrict__ y1,
    const int* __restrict__ offs, const int* __restrict__ re, const int* __restrict__ rs,
    const float* __restrict__ rw, float4* __restrict__ out4) {
  int t = blockIdx.x;
  int i = threadIdx.x;
  size_t r0 = (size_t)(offs[re[2 * t]] + rs[2 * t]) * 256 + i;
  size_t r1 = (size_t)(offs[re[2 * t + 1]] + rs[2 * t + 1]) * 256 + i;
  float w0 = rw[2 * t], w1 = rw[2 * t + 1];
  float4 a0 = y0[r0], a1 = y1[r0];
  float4 b0 = y0[r1], b1 = y1[r1];
  out4[(size_t)t * 256 + i] = make_float4(
      w0 * (a0.x + a1.x) + w1 * (b0.x + b1.x),
      w0 * (a0.y + a1.y) + w1 * (b0.y + b1.y),
      w0 * (a0.z + a1.z) + w1 * (b0.z + b1.z),
      w0 * (a0.w + a1.w) + w1 * (b0.w + b1.w));
}

extern "C" void kernel_launch(void* const* d_in, const int* in_sizes, int n_in,
                              void* d_out, int out_size, void* d_ws, size_t ws_size,
                              hipStream_t stream) {
  const float* x  = (const float*)d_in[0];
  const float* Wg = (const float*)d_in[1];
  const float* W1 = (const float*)d_in[2];
  const float* W2 = (const float*)d_in[3];
  const float* W3 = (const float*)d_in[4];
  float* out = (float*)d_out;
  char* ws = (char*)d_ws;

  int*   counts = (int*)(ws + 0);
  int*   offs   = (int*)(ws + 256);
  int*   tlist  = (int*)(ws + 512);
  int*   re     = (int*)(ws + 131584);
  int*   rs     = (int*)(ws + 164352);
  float* rw     = (float*)(ws + 197120);
  short* xbf    = (short*)(ws + 229888);
  short* hmat   = (short*)(ws + 8618496);
  short* W3bf   = (short*)(ws + 54755840);
  short* W1bf   = (short*)(ws + 100893184);
  short* W2bf   = (short*)(ws + 147030528);
  float* ypart0 = (float*)(ws + 100893184);   // aliases W1bf (dead after ffn1)
  float* ypart1 = (float*)(ws + 147030528);   // aliases W2bf (dead after ffn1)

  convert_kernel<<<dim3(4096, 3), 256, 0, stream>>>(W1, W2, W3, W1bf, W2bf, W3bf, counts);
  gating_fast_kernel<<<T_TOK, 64, 0, stream>>>(x, Wg, xbf, counts, tlist, re, rs, rw);
  offsets_kernel<<<1, 64, 0, stream>>>(counts, offs);
  ffn1_fast_kernel<<<dim3(HDIM / 64, T_TOK / 128, NEXP), 256, 0, stream>>>(
      xbf, W1bf, W2bf, counts, offs, tlist, hmat);
  ffn2_fast_kernel<<<dim3((DDIM / 128) * KSPLIT, T_TOK / 128, NEXP), 256, 0, stream>>>(
      hmat, W3bf, counts, offs, ypart0, ypart1);
  combine_kernel<<<T_TOK, 256, 0, stream>>>((const float4*)ypart0, (const float4*)ypart1,
                                            offs, re, rs, rw, (float4*)out);
}

// Round 4
// 539.854 us; speedup vs baseline: 1.2107x; 1.1525x over previous
//
#include <hip/hip_runtime.h>
#include <hip/hip_bf16.h>
#include <stdint.h>

// MoE FFN top-2 sparse, bf16 MFMA, global_load_lds staging. T=4096, D=1024, H=2816, E=8.
// Round 4: atomic-free routing (gating_score + single-block route scan).
//
// ws layout (needs 193,167,872 B):
//   [0]         counts[8]
//   [256]       offs[8]
//   [512]       tlist[E*T] int        131072
//   [131584]    re[2T] int            32768   (expert per token slot)
//   [164352]    rs[2T] int            32768   (slot within expert list)
//   [197120]    rw[2T] float          32768   (gate weight)
//   [229888]    xbf[T*D] bf16         8388608
//   [8618496]   hmat[8192*H] bf16     46137344
//   [54755840]  W3bf bf16             46137344
//   [100893184] W1bf bf16             46137344   <-- ypart0[8192*D] fp32 aliases after ffn1
//   [147030528] W2bf bf16             46137344   <-- ypart1[8192*D] fp32 aliases after ffn1

#define T_TOK 4096
#define DDIM 1024
#define HDIM 2816
#define NEXP 8

typedef __attribute__((ext_vector_type(8))) short short8;
typedef __attribute__((ext_vector_type(4))) short short4v;
typedef __attribute__((ext_vector_type(4))) float floatx4;

__device__ __forceinline__ short f2bf(float f) {
  union { float f; unsigned int u; } v; v.f = f;
  unsigned int u = v.u;
  u += 0x7FFFu + ((u >> 16) & 1u);   // round-to-nearest-even
  return (short)(u >> 16);
}

// async global->LDS, 16B per lane. LDS dest = wave-uniform base + lane*16.
__device__ __forceinline__ void gl2lds16(const void* g, void* l) {
  __builtin_amdgcn_global_load_lds(
      (const __attribute__((address_space(1))) void*)g,
      (__attribute__((address_space(3))) void*)l, 16, 0, 0);
}

// fp32 -> bf16 weight conversion. Coalesced: 16B/lane float4 read, 8B/lane write,
// grid-stride. blockIdx.y picks W1/W2/W3.
#define CONV_ELEM4 5767168   // (8*2816*1024)/4 float4s per matrix
__global__ __launch_bounds__(256) void convert_kernel(
    const float* __restrict__ W1, const float* __restrict__ W2, const float* __restrict__ W3,
    short* __restrict__ W1bf, short* __restrict__ W2bf, short* __restrict__ W3bf) {
  int z = blockIdx.y;
  const float4* src = (const float4*)((z == 0) ? W1 : (z == 1) ? W2 : W3);
  short4v* dst = (short4v*)((z == 0) ? W1bf : (z == 1) ? W2bf : W3bf);
  size_t stride = (size_t)gridDim.x * 256;
  for (size_t i = (size_t)blockIdx.x * 256 + threadIdx.x; i < CONV_ELEM4; i += stride) {
    float4 v = src[i];
    dst[i] = (short4v){f2bf(v.x), f2bf(v.y), f2bf(v.z), f2bf(v.w)};
  }
}

// gating scores + top-2 selection. NO atomics: just per-token (expert, weight)
// pairs re/rw, plus the bf16 cast of x. Routing lists built by route_kernel.
__global__ __launch_bounds__(64) void gating_score_kernel(const float* __restrict__ x,
    const float* __restrict__ Wg, short* __restrict__ xbf,
    int* __restrict__ re, float* __restrict__ rw) {
  int t = blockIdx.x;
  int lane = threadIdx.x;
  const float* xt = x + (size_t)t * DDIM;
  float xr[16];
#pragma unroll
  for (int j = 0; j < 16; ++j) xr[j] = xt[j * 64 + lane];
  short* xbt = xbf + (size_t)t * DDIM;
#pragma unroll
  for (int j = 0; j < 16; ++j) xbt[j * 64 + lane] = f2bf(xr[j]);
  float s[NEXP];
#pragma unroll
  for (int e = 0; e < NEXP; ++e) {
    const float* wge = Wg + e * DDIM;
    float p = 0.f;
#pragma unroll
    for (int j = 0; j < 16; ++j) p += xr[j] * wge[j * 64 + lane];
#pragma unroll
    for (int o = 32; o > 0; o >>= 1) p += __shfl_xor(p, o, 64);
    s[e] = p;
  }
  if (lane == 0) {
    int e1 = 0; float s1 = s[0];
#pragma unroll
    for (int e = 1; e < NEXP; ++e) if (s[e] > s1) { s1 = s[e]; e1 = e; }
    int e2 = -1; float s2 = -1e30f;
#pragma unroll
    for (int e = 0; e < NEXP; ++e) if (e != e1 && s[e] > s2) { s2 = s[e]; e2 = e; }
    re[2 * t] = e1;     rw[2 * t] = s1;
    re[2 * t + 1] = e2; rw[2 * t + 1] = s2;
  }
}

// Deterministic routing build, single workgroup, zero global atomics.
// 1024 threads, each owns 8 of the 8192 (token,k) entries. Per-thread expert
// histogram -> per-expert exclusive scan over threads (wave e scans expert e)
// -> slot assignment. Emits counts, offs, rs (slot within expert), tlist.
__global__ __launch_bounds__(1024) void route_kernel(const int* __restrict__ re,
    int* __restrict__ counts, int* __restrict__ offs,
    int* __restrict__ rs, int* __restrict__ tlist) {
  __shared__ int H[NEXP * 1024];   // 32 KiB
  __shared__ int totS[NEXP];
  int tid = threadIdx.x;
  int myre[8];
  int cnt[NEXP];
#pragma unroll
  for (int e = 0; e < NEXP; ++e) cnt[e] = 0;
  const int4* re4 = (const int4*)(re + tid * 8);
  int4 a = re4[0], b = re4[1];
  myre[0] = a.x; myre[1] = a.y; myre[2] = a.z; myre[3] = a.w;
  myre[4] = b.x; myre[5] = b.y; myre[6] = b.z; myre[7] = b.w;
#pragma unroll
  for (int j = 0; j < 8; ++j) cnt[myre[j]]++;
#pragma unroll
  for (int e = 0; e < NEXP; ++e) H[e * 1024 + tid] = cnt[e];
  __syncthreads();
  int wave = tid >> 6, lane = tid & 63;
  if (wave < NEXP) {
    int run = 0;
    for (int c = 0; c < 16; ++c) {
      int i = c * 64 + lane;
      int v = H[wave * 1024 + i];
      int sc = v;
#pragma unroll
      for (int o = 1; o < 64; o <<= 1) {
        int u = __shfl_up(sc, o, 64);
        if (lane >= o) sc += u;
      }
      int tot = __shfl(sc, 63, 64);
      H[wave * 1024 + i] = run + sc - v;   // exclusive prefix within expert
      run += tot;
    }
    if (lane == 0) totS[wave] = run;
  }
  __syncthreads();
  if (tid == 0) {
    int run = 0;
    for (int e = 0; e < NEXP; ++e) {
      offs[e] = run; counts[e] = totS[e]; run += totS[e];
    }
  }
  int pos[NEXP];
#pragma unroll
  for (int e = 0; e < NEXP; ++e) pos[e] = H[e * 1024 + tid];
#pragma unroll
  for (int j = 0; j < 8; ++j) {
    int e = myre[j];
    int slot = pos[e]++;
    int idx = tid * 8 + j;
    rs[idx] = slot;
    tlist[e * T_TOK + slot] = idx >> 1;
  }
}

// ffn1: hmat[row, h] = silu(x@W1^T) * (x@W2^T). BM=128 x BN=64 x BK=32, 4 waves 2x2,
// dual accumulators, global_load_lds(16B) staging, unpadded m97 LDS layout.
__global__ __launch_bounds__(256) void ffn1_fast_kernel(const short* __restrict__ xbf,
    const short* __restrict__ W1bf, const short* __restrict__ W2bf,
    const int* __restrict__ counts, const int* __restrict__ offs,
    const int* __restrict__ tlist, short* __restrict__ hmat) {
  int e = blockIdx.z;
  int cnt = counts[e];
  int m0 = blockIdx.y * 128;
  if (m0 >= cnt) return;
  int n0 = blockIdx.x * 64;
  __shared__ __attribute__((aligned(16))) short As[128 * 32];
  __shared__ __attribute__((aligned(16))) short Bs1[64 * 32];
  __shared__ __attribute__((aligned(16))) short Bs2[64 * 32];
  __shared__ int toks[128];
  int tid = threadIdx.x;
  if (tid < 128) {
    int m = m0 + tid;
    toks[tid] = tlist[e * T_TOK + (m < cnt ? m : cnt - 1)];
  }
  __syncthreads();
  int lane = tid & 63, w = tid >> 6;
  int wr = w >> 1, wc = w & 1;
  int lrow = lane & 15, lq = lane >> 4;
  int lr = lane >> 2;          // 0..15: row within a 16-row sweep
  int lc = (lane & 3) * 8;     // short offset within a 64B row
  const short* pA0 = xbf + (size_t)toks[w * 32 + lr] * DDIM + lc;
  const short* pA1 = xbf + (size_t)toks[w * 32 + 16 + lr] * DDIM + lc;
  const short* b1e = W1bf + (size_t)e * HDIM * DDIM;
  const short* b2e = W2bf + (size_t)e * HDIM * DDIM;
  const short* pB1 = b1e + (size_t)(n0 + w * 16 + lr) * DDIM + lc;
  const short* pB2 = b2e + (size_t)(n0 + w * 16 + lr) * DDIM + lc;
  void* lA0 = (void*)&As[(2 * w) * 512];
  void* lA1 = (void*)&As[(2 * w + 1) * 512];
  void* lB1 = (void*)&Bs1[w * 512];
  void* lB2 = (void*)&Bs2[w * 512];
  floatx4 accg[4][2], accu[4][2];
#pragma unroll
  for (int i = 0; i < 4; ++i)
#pragma unroll
    for (int j = 0; j < 2; ++j) {
      accg[i][j] = (floatx4){0.f, 0.f, 0.f, 0.f};
      accu[i][j] = (floatx4){0.f, 0.f, 0.f, 0.f};
    }
  for (int kk = 0; kk < DDIM; kk += 32) {
    gl2lds16(pA0, lA0);
    gl2lds16(pA1, lA1);
    gl2lds16(pB1, lB1);
    gl2lds16(pB2, lB2);
    pA0 += 32; pA1 += 32; pB1 += 32; pB2 += 32;
    __syncthreads();
    short8 a[4], b1[2], b2[2];
#pragma unroll
    for (int mf = 0; mf < 4; ++mf)
      a[mf] = *(short8*)&As[(wr * 64 + mf * 16 + lrow) * 32 + lq * 8];
#pragma unroll
    for (int nf = 0; nf < 2; ++nf) {
      b1[nf] = *(short8*)&Bs1[(wc * 32 + nf * 16 + lrow) * 32 + lq * 8];
      b2[nf] = *(short8*)&Bs2[(wc * 32 + nf * 16 + lrow) * 32 + lq * 8];
    }
#pragma unroll
    for (int mf = 0; mf < 4; ++mf)
#pragma unroll
      for (int nf = 0; nf < 2; ++nf) {
        accg[mf][nf] = __builtin_amdgcn_mfma_f32_16x16x32_bf16(a[mf], b1[nf], accg[mf][nf], 0, 0, 0);
        accu[mf][nf] = __builtin_amdgcn_mfma_f32_16x16x32_bf16(a[mf], b2[nf], accu[mf][nf], 0, 0, 0);
      }
    __syncthreads();
  }
  int base = offs[e];
#pragma unroll
  for (int mf = 0; mf < 4; ++mf)
#pragma unroll
    for (int r = 0; r < 4; ++r) {
      int mloc = wr * 64 + mf * 16 + lq * 4 + r;
      if (m0 + mloc < cnt) {
        size_t row = (size_t)(base + m0 + mloc);
#pragma unroll
        for (int nf = 0; nf < 2; ++nf) {
          float g = accg[mf][nf][r];
          float u = accu[mf][nf][r];
          float h = g / (1.f + __expf(-g)) * u;
          hmat[row * HDIM + n0 + wc * 32 + nf * 16 + lrow] = f2bf(h);
        }
      }
    }
}

// ffn2: split-K x2. ypart[ks][row, :] = hmat_row[khalf] @ W3[khalf]^T.
#define KSPLIT 2
#define KHALF (HDIM / KSPLIT)   // 1408
__global__ __launch_bounds__(256) void ffn2_fast_kernel(const short* __restrict__ hmat,
    const short* __restrict__ W3bf,
    const int* __restrict__ counts, const int* __restrict__ offs,
    float* __restrict__ ypart0, float* __restrict__ ypart1) {
  int e = blockIdx.z;
  int cnt = counts[e];
  int m0 = blockIdx.y * 128;
  if (m0 >= cnt) return;
  int ks = blockIdx.x >> 3;            // 0..1: K-split index
  int n0 = (blockIdx.x & 7) * 128;     // 0..7: n-tile
  int k0 = ks * KHALF;
  float* ypart = ks ? ypart1 : ypart0;
  int base = offs[e];
  __shared__ __attribute__((aligned(16))) short As[128 * 32];
  __shared__ __attribute__((aligned(16))) short Bs[128 * 32];
  int tid = threadIdx.x;
  int lane = tid & 63, w = tid >> 6;
  int wr = w >> 1, wc = w & 1;
  int lrow = lane & 15, lq = lane >> 4;
  int lr = lane >> 2;
  int lc = (lane & 3) * 8;
  int gA0 = m0 + w * 32 + lr;      gA0 = gA0 < cnt ? gA0 : cnt - 1;
  int gA1 = m0 + w * 32 + 16 + lr; gA1 = gA1 < cnt ? gA1 : cnt - 1;
  const short* pA0 = hmat + (size_t)(base + gA0) * HDIM + k0 + lc;
  const short* pA1 = hmat + (size_t)(base + gA1) * HDIM + k0 + lc;
  const short* W3e = W3bf + (size_t)e * DDIM * HDIM;
  const short* pB0 = W3e + (size_t)(n0 + w * 32 + lr) * HDIM + k0 + lc;
  const short* pB1 = W3e + (size_t)(n0 + w * 32 + 16 + lr) * HDIM + k0 + lc;
  void* lA0 = (void*)&As[(2 * w) * 512];
  void* lA1 = (void*)&As[(2 * w + 1) * 512];
  void* lB0 = (void*)&Bs[(2 * w) * 512];
  void* lB1 = (void*)&Bs[(2 * w + 1) * 512];
  floatx4 acc[4][4];
#pragma unroll
  for (int i = 0; i < 4; ++i)
#pragma unroll
    for (int j = 0; j < 4; ++j) acc[i][j] = (floatx4){0.f, 0.f, 0.f, 0.f};
  for (int kk = 0; kk < KHALF; kk += 32) {
    gl2lds16(pA0, lA0);
    gl2lds16(pA1, lA1);
    gl2lds16(pB0, lB0);
    gl2lds16(pB1, lB1);
    pA0 += 32; pA1 += 32; pB0 += 32; pB1 += 32;
    __syncthreads();
    short8 a[4], b[4];
#pragma unroll
    for (int mf = 0; mf < 4; ++mf)
      a[mf] = *(short8*)&As[(wr * 64 + mf * 16 + lrow) * 32 + lq * 8];
#pragma unroll
    for (int nf = 0; nf < 4; ++nf)
      b[nf] = *(short8*)&Bs[(wc * 64 + nf * 16 + lrow) * 32 + lq * 8];
#pragma unroll
    for (int mf = 0; mf < 4; ++mf)
#pragma unroll
      for (int nf = 0; nf < 4; ++nf)
        acc[mf][nf] = __builtin_amdgcn_mfma_f32_16x16x32_bf16(a[mf], b[nf], acc[mf][nf], 0, 0, 0);
    __syncthreads();
  }
#pragma unroll
  for (int mf = 0; mf < 4; ++mf)
#pragma unroll
    for (int r = 0; r < 4; ++r) {
      int mloc = wr * 64 + mf * 16 + lq * 4 + r;
      if (m0 + mloc < cnt) {
        float* orow = ypart + (size_t)(base + m0 + mloc) * DDIM + n0 + wc * 64 + lrow;
#pragma unroll
        for (int nf = 0; nf < 4; ++nf)
          orow[nf * 16] = acc[mf][nf][r];
      }
    }
}

// out[t,:] = w0*(y0[r0]+y1[r0]) + w1*(y0[r1]+y1[r1])  (overwrites out; no atomics)
__global__ __launch_bounds__(256) void combine_kernel(const float4* __restrict__ y0,
    const float4* __restrict__ y1,
    const int* __restrict__ offs, const int* __restrict__ re, const int* __restrict__ rs,
    const float* __restrict__ rw, float4* __restrict__ out4) {
  int t = blockIdx.x;
  int i = threadIdx.x;
  size_t r0 = (size_t)(offs[re[2 * t]] + rs[2 * t]) * 256 + i;
  size_t r1 = (size_t)(offs[re[2 * t + 1]] + rs[2 * t + 1]) * 256 + i;
  float w0 = rw[2 * t], w1 = rw[2 * t + 1];
  float4 a0 = y0[r0], a1 = y1[r0];
  float4 b0 = y0[r1], b1 = y1[r1];
  out4[(size_t)t * 256 + i] = make_float4(
      w0 * (a0.x + a1.x) + w1 * (b0.x + b1.x),
      w0 * (a0.y + a1.y) + w1 * (b0.y + b1.y),
      w0 * (a0.z + a1.z) + w1 * (b0.z + b1.z),
      w0 * (a0.w + a1.w) + w1 * (b0.w + b1.w));
}

extern "C" void kernel_launch(void* const* d_in, const int* in_sizes, int n_in,
                              void* d_out, int out_size, void* d_ws, size_t ws_size,
                              hipStream_t stream) {
  const float* x  = (const float*)d_in[0];
  const float* Wg = (const float*)d_in[1];
  const float* W1 = (const float*)d_in[2];
  const float* W2 = (const float*)d_in[3];
  const float* W3 = (const float*)d_in[4];
  float* out = (float*)d_out;
  char* ws = (char*)d_ws;

  int*   counts = (int*)(ws + 0);
  int*   offs   = (int*)(ws + 256);
  int*   tlist  = (int*)(ws + 512);
  int*   re     = (int*)(ws + 131584);
  int*   rs     = (int*)(ws + 164352);
  float* rw     = (float*)(ws + 197120);
  short* xbf    = (short*)(ws + 229888);
  short* hmat   = (short*)(ws + 8618496);
  short* W3bf   = (short*)(ws + 54755840);
  short* W1bf   = (short*)(ws + 100893184);
  short* W2bf   = (short*)(ws + 147030528);
  float* ypart0 = (float*)(ws + 100893184);   // aliases W1bf (dead after ffn1)
  float* ypart1 = (float*)(ws + 147030528);   // aliases W2bf (dead after ffn1)

  convert_kernel<<<dim3(4096, 3), 256, 0, stream>>>(W1, W2, W3, W1bf, W2bf, W3bf);
  gating_score_kernel<<<T_TOK, 64, 0, stream>>>(x, Wg, xbf, re, rw);
  route_kernel<<<1, 1024, 0, stream>>>(re, counts, offs, rs, tlist);
  ffn1_fast_kernel<<<dim3(HDIM / 64, T_TOK / 128, NEXP), 256, 0, stream>>>(
      xbf, W1bf, W2bf, counts, offs, tlist, hmat);
  ffn2_fast_kernel<<<dim3((DDIM / 128) * KSPLIT, T_TOK / 128, NEXP), 256, 0, stream>>>(
      hmat, W3bf, counts, offs, ypart0, ypart1);
  combine_kernel<<<T_TOK, 256, 0, stream>>>((const float4*)ypart0, (const float4*)ypart1,
                                            offs, re, rs, rw, (float4*)out);
}